// Round 1
// baseline (307.860 us; speedup 1.0000x reference)
//
#include <hip/hip_runtime.h>
#include <math.h>

#define Bn   32768
#define TWOB 65536
#define Dd   512
#define Kk   256
#define MAXM 1024
#define MC   4

typedef unsigned short ushort_t;
typedef __attribute__((ext_vector_type(8))) unsigned short us8;
typedef __attribute__((ext_vector_type(8))) __bf16 bf16x8;
typedef __attribute__((ext_vector_type(4))) float f32x4;

__device__ __forceinline__ const float* cfrow(const float* X, int i) {
    // cf[i] = i < B ? X[i][0][:] : X[i-B][1][:]
    return X + (i < Bn ? (size_t)i * (2 * Dd) : (size_t)(i - Bn) * (2 * Dd) + Dd);
}

__device__ __forceinline__ unsigned short f2bf(float f) {
    union { float f; unsigned int u; } v; v.f = f;
    unsigned int r = v.u + 0x7fffu + ((v.u >> 16) & 1u);  // RNE
    return (unsigned short)(r >> 16);
}

// ---- 1) counts + member lists -------------------------------------------
__global__ void k_count(const int* __restrict__ subject, int* cnt, int* mlist) {
    int i = blockIdx.x * 256 + threadIdx.x;
    if (i >= TWOB) return;
    int s = subject[i < Bn ? i : i - Bn];
    int pos = atomicAdd(&cnt[s], 1);
    if (pos < MAXM) mlist[s * MAXM + pos] = i;
}

// ---- 2) centroid partial sums (gather by member list) -------------------
__global__ void k_cent(const float* __restrict__ X, const int* __restrict__ cnt,
                       const int* __restrict__ mlist, float* cen_acc) {
    int k = blockIdx.y;
    int n = cnt[k]; if (n > MAXM) n = MAXM;
    int per = (n + MC - 1) / MC;
    int m0 = blockIdx.x * per, m1 = min(m0 + per, n);
    if (m0 >= m1) return;
    int t = threadIdx.x;                       // 256 threads -> 2 d-cols each
    float a0 = 0.f, a1 = 0.f;
    for (int m = m0; m < m1; ++m) {
        const float* row = cfrow(X, mlist[k * MAXM + m]);
        a0 += row[t];
        a1 += row[t + 256];
    }
    atomicAdd(&cen_acc[k * Dd + t], a0);
    atomicAdd(&cen_acc[k * Dd + t + 256], a1);
}

// ---- 3) finalize centroids: divide, bf16 copy, ||cen||_F^2 --------------
__global__ void k_cenfin(float* cen, const int* __restrict__ cnt,
                         ushort_t* cenb, float* scal) {
    int k = blockIdx.x, t = threadIdx.x;
    float c = (float)cnt[k];
    float inv = c > 0.f ? 1.0f / c : 0.f;
    float v0 = cen[k * Dd + t] * inv, v1 = cen[k * Dd + t + 256] * inv;
    cen[k * Dd + t] = v0;           cen[k * Dd + t + 256] = v1;
    cenb[k * Dd + t] = f2bf(v0);    cenb[k * Dd + t + 256] = f2bf(v1);
    float ss = v0 * v0 + v1 * v1;
    #pragma unroll
    for (int o = 32; o; o >>= 1) ss += __shfl_xor(ss, o);
    __shared__ float w[4];
    int lane = t & 63, wid = t >> 6;
    if (lane == 0) w[wid] = ss;
    __syncthreads();
    if (t == 0) atomicAdd(&scal[1], w[0] + w[1] + w[2] + w[3]);
}

// ---- 4) per-row distance + ||cf||_F^2 -----------------------------------
__global__ void k_dist(const float* __restrict__ X, const int* __restrict__ subject,
                       const float* __restrict__ cen, float* sumsqrt, float* scal) {
    int wid = threadIdx.x >> 6, lane = threadIdx.x & 63;
    int i = blockIdx.x * 4 + wid;                 // one wave per row
    int s = subject[i < Bn ? i : i - Bn];
    const float* row = cfrow(X, i);
    const float* c = cen + (size_t)s * Dd;
    float d2 = 0.f, x2 = 0.f;
    #pragma unroll
    for (int j = 0; j < 2; ++j) {
        float4 x  = *(const float4*)(row + lane * 8 + j * 4);
        float4 cc = *(const float4*)(c   + lane * 8 + j * 4);
        float e;
        e = x.x - cc.x; d2 += e * e; x2 += x.x * x.x;
        e = x.y - cc.y; d2 += e * e; x2 += x.y * x.y;
        e = x.z - cc.z; d2 += e * e; x2 += x.z * x.z;
        e = x.w - cc.w; d2 += e * e; x2 += x.w * x.w;
    }
    #pragma unroll
    for (int o = 32; o; o >>= 1) { d2 += __shfl_xor(d2, o); x2 += __shfl_xor(x2, o); }
    __shared__ float w[4];
    if (lane == 0) {
        atomicAdd(&sumsqrt[s], sqrtf(sqrtf(d2)));   // sqrt(dist) = (d2)^(1/4)
        w[wid] = x2;
    }
    __syncthreads();
    if (threadIdx.x == 0) atomicAdd(&scal[0], w[0] + w[1] + w[2] + w[3]);
}

// ---- 5) density: stats -> sort -> quantile clip -> normalize -> colscale -
__global__ void k_density(const float* __restrict__ sumsqrt, const int* __restrict__ cnt,
                          const float* __restrict__ scal, float* colscale) {
    __shared__ float sd[Kk];
    __shared__ float sb[Kk];
    int t = threadIdx.x;
    float c = (float)cnt[t];
    bool valid = c > 1.f;
    float draw = valid ? (sumsqrt[t] / c) / logf(c + 10.f) : -INFINITY;
    sb[t] = draw;
    __syncthreads();
    for (int o = 128; o; o >>= 1) { if (t < o) sb[t] = fmaxf(sb[t], sb[t + o]); __syncthreads(); }
    float dmax = sb[0];
    __syncthreads();
    float dens = valid ? draw : dmax;
    sd[t] = dens;
    __syncthreads();
    // bitonic sort ascending (256 values, 256 threads)
    for (int ksz = 2; ksz <= Kk; ksz <<= 1) {
        for (int j = ksz >> 1; j > 0; j >>= 1) {
            int ixj = t ^ j;
            if (ixj > t) {
                float a = sd[t], b = sd[ixj];
                bool up = ((t & ksz) == 0);
                if ((a > b) == up) { sd[t] = b; sd[ixj] = a; }
            }
            __syncthreads();
        }
    }
    float p1 = 0.1f * (Kk - 1); int i1 = (int)p1; float f1 = p1 - (float)i1;
    float p9 = 0.9f * (Kk - 1); int i9 = (int)p9; float f9 = p9 - (float)i9;
    float q10 = sd[i1] + f1 * (sd[i1 + 1] - sd[i1]);
    float q90 = sd[i9] + f9 * (sd[i9 + 1] - sd[i9]);
    float dcl = fminf(fmaxf(dens, q10), q90);
    __syncthreads();
    sb[t] = dcl;
    __syncthreads();
    for (int o = 128; o; o >>= 1) { if (t < o) sb[t] += sb[t + o]; __syncthreads(); }
    float mean = sb[0] / (float)Kk;
    float df = 0.1f * dcl / mean;
    colscale[t] = 1.0f / (sqrtf(scal[0]) * sqrtf(scal[1]) * df);
}

// ---- 6) fused bf16-MFMA GEMM (cf @ cen^T) + masked log-softmax loss -----
__global__ __launch_bounds__(512)
void k_loss(const float* __restrict__ X, const int* __restrict__ subject,
            const ushort_t* __restrict__ cenb, const float* __restrict__ colscale,
            float* loss_sum) {
    __shared__ __align__(16) ushort_t Alds[128 * 32];   // 8 KB
    __shared__ __align__(16) ushort_t Blds[256 * 32];   // 16 KB
    __shared__ float cs[256];
    __shared__ int sseg[128];
    __shared__ float blockloss;
    int t = threadIdx.x;
    int wid = t >> 6, lane = t & 63;
    int row0 = blockIdx.x * 128;
    if (t < 256) cs[t] = colscale[t];
    if (t < 128) { int gr = row0 + t; sseg[t] = subject[gr < Bn ? gr : gr - Bn]; }
    if (t == 0) blockloss = 0.f;

    f32x4 acc[16] = {};

    int ar = t >> 2, aq = t & 3;   // A staging: 4 threads/row, 8 floats each
    int bc = t >> 1, bh = t & 1;   // B staging: 2 threads/row, 16 bf16 each
    const float* asrc_base = cfrow(X, row0 + ar);

    for (int k0 = 0; k0 < Dd; k0 += 32) {
        __syncthreads();
        {   // stage A (fp32 -> bf16, XOR-swizzled 16B chunks)
            const float* src = asrc_base + k0 + aq * 8;
            float4 x0 = *(const float4*)src;
            float4 x1 = *(const float4*)(src + 4);
            us8 pk;
            pk[0] = f2bf(x0.x); pk[1] = f2bf(x0.y); pk[2] = f2bf(x0.z); pk[3] = f2bf(x0.w);
            pk[4] = f2bf(x1.x); pk[5] = f2bf(x1.y); pk[6] = f2bf(x1.z); pk[7] = f2bf(x1.w);
            int sw = aq ^ ((ar >> 1) & 3);
            *(us8*)(Alds + ar * 32 + sw * 8) = pk;
        }
        {   // stage B (cen bf16, XOR-swizzled)
            const ushort_t* src = cenb + bc * Dd + k0 + bh * 16;
            us8 b0 = *(const us8*)src;
            us8 b1 = *(const us8*)(src + 8);
            int r3 = (bc >> 1) & 3;
            *(us8*)(Blds + bc * 32 + ((2 * bh    ) ^ r3) * 8) = b0;
            *(us8*)(Blds + bc * 32 + ((2 * bh + 1) ^ r3) * 8) = b1;
        }
        __syncthreads();
        int q = lane >> 4;
        int rl = wid * 16 + (lane & 15);
        us8 araw = *(const us8*)(Alds + rl * 32 + (q ^ ((rl >> 1) & 3)) * 8);
        bf16x8 a = __builtin_bit_cast(bf16x8, araw);
        #pragma unroll
        for (int ct = 0; ct < 16; ++ct) {
            int cc = ct * 16 + (lane & 15);
            us8 braw = *(const us8*)(Blds + cc * 32 + (q ^ ((cc >> 1) & 3)) * 8);
            bf16x8 b = __builtin_bit_cast(bf16x8, braw);
            acc[ct] = __builtin_amdgcn_mfma_f32_16x16x32_bf16(a, b, acc[ct], 0, 0, 0);
        }
    }

    // epilogue: per-row masked lse + sum over 256 cols (16 lanes x 16 frags)
    int q = lane >> 4, cl = lane & 15;
    float lossw = 0.f;
    #pragma unroll
    for (int reg = 0; reg < 4; ++reg) {
        int rl = wid * 16 + q * 4 + reg;       // C layout: row=(lane>>4)*4+reg
        int s = sseg[rl];
        float mymax = -INFINITY;
        #pragma unroll
        for (int ct = 0; ct < 16; ++ct) {
            int c = ct * 16 + cl;
            float v = acc[ct][reg] * cs[c];
            if (c != s) mymax = fmaxf(mymax, v);
        }
        #pragma unroll
        for (int o = 1; o < 16; o <<= 1) mymax = fmaxf(mymax, __shfl_xor(mymax, o));
        float se = 0.f, sv = 0.f;
        #pragma unroll
        for (int ct = 0; ct < 16; ++ct) {
            int c = ct * 16 + cl;
            float v = acc[ct][reg] * cs[c];
            if (c != s) { se += __expf(v - mymax); sv += v; }
        }
        #pragma unroll
        for (int o = 1; o < 16; o <<= 1) { se += __shfl_xor(se, o); sv += __shfl_xor(sv, o); }
        if (cl == 0) lossw += (__logf(se) + mymax) - sv * (1.0f / (float)(Kk - 1));
    }
    if (cl == 0) atomicAdd(&blockloss, lossw);
    __syncthreads();
    if (t == 0) atomicAdd(loss_sum, blockloss);
}

// ---- 7) final scalar ------------------------------------------------------
__global__ void k_final(const float* __restrict__ loss_sum, float* out) {
    out[0] = loss_sum[0] / (float)TWOB;
}

extern "C" void kernel_launch(void* const* d_in, const int* in_sizes, int n_in,
                              void* d_out, int out_size, void* d_ws, size_t ws_size,
                              hipStream_t stream) {
    const float* X = (const float*)d_in[0];
    const int* subject = (const int*)d_in[1];
    float* out = (float*)d_out;
    float* ws = (float*)d_ws;

    float* cen       = ws;                                   // K*D fp32 (acc -> final)
    int*   cnt       = (int*)(ws + Kk * Dd);                 // K
    float* sumsqrt   = ws + Kk * Dd + Kk;                    // K
    float* scal      = ws + Kk * Dd + 2 * Kk;                // [0]=||cf||^2 [1]=||cen||^2 [2]=loss
    float* colscale  = ws + Kk * Dd + 2 * Kk + 8;            // K
    ushort_t* cenb   = (ushort_t*)(ws + Kk * Dd + 3 * Kk + 8);         // K*D bf16
    int*   mlist     = (int*)(ws + Kk * Dd + 3 * Kk + 8 + (Kk * Dd) / 2); // K*MAXM

    // zero all accumulators (cen_acc, cnt, sumsqrt, scalars)
    hipMemsetAsync(ws, 0, (size_t)(Kk * Dd + 2 * Kk + 8) * sizeof(float), stream);

    k_count  <<<TWOB / 256, 256, 0, stream>>>(subject, cnt, mlist);
    k_cent   <<<dim3(MC, Kk), 256, 0, stream>>>(X, cnt, mlist, cen);
    k_cenfin <<<Kk, 256, 0, stream>>>(cen, cnt, cenb, scal);
    k_dist   <<<TWOB / 4, 256, 0, stream>>>(X, subject, cen, sumsqrt, scal);
    k_density<<<1, 256, 0, stream>>>(sumsqrt, cnt, scal, colscale);
    k_loss   <<<TWOB / 128, 512, 0, stream>>>(X, subject, cenb, colscale, &scal[2]);
    k_final  <<<1, 1, 0, stream>>>(&scal[2], out);
}

// Round 2
// 118.814 us; speedup vs baseline: 2.5911x; 2.5911x over previous
//
#include <hip/hip_runtime.h>
#include <math.h>

#define Bn   32768
#define TWOB 65536
#define Dd   512
#define Kk   256
#define MAXM 1024
#define MC   4

typedef unsigned short ushort_t;
typedef __attribute__((ext_vector_type(8))) unsigned short us8;
typedef __attribute__((ext_vector_type(8))) __bf16 bf16x8;
typedef __attribute__((ext_vector_type(4))) float f32x4;

__device__ __forceinline__ const float* cfrow(const float* X, int i) {
    // cf[i] = i < B ? X[i][0][:] : X[i-B][1][:]
    return X + (i < Bn ? (size_t)i * (2 * Dd) : (size_t)(i - Bn) * (2 * Dd) + Dd);
}

__device__ __forceinline__ unsigned short f2bf(float f) {
    union { float f; unsigned int u; } v; v.f = f;
    unsigned int r = v.u + 0x7fffu + ((v.u >> 16) & 1u);  // RNE
    return (unsigned short)(r >> 16);
}

// ---- 1) counts + member lists -------------------------------------------
__global__ void k_count(const int* __restrict__ subject, int* cnt, int* mlist) {
    int i = blockIdx.x * 256 + threadIdx.x;
    if (i >= TWOB) return;
    int s = subject[i < Bn ? i : i - Bn];
    int pos = atomicAdd(&cnt[s], 1);
    if (pos < MAXM) mlist[s * MAXM + pos] = i;
}

// ---- 2) centroid partial sums (gather by member list) -------------------
__global__ void k_cent(const float* __restrict__ X, const int* __restrict__ cnt,
                       const int* __restrict__ mlist, float* cen_acc) {
    int k = blockIdx.y;
    int n = cnt[k]; if (n > MAXM) n = MAXM;
    int per = (n + MC - 1) / MC;
    int m0 = blockIdx.x * per, m1 = min(m0 + per, n);
    if (m0 >= m1) return;
    int t = threadIdx.x;                       // 256 threads -> 2 d-cols each
    float a0 = 0.f, a1 = 0.f;
    for (int m = m0; m < m1; ++m) {
        const float* row = cfrow(X, mlist[k * MAXM + m]);
        a0 += row[t];
        a1 += row[t + 256];
    }
    atomicAdd(&cen_acc[k * Dd + t], a0);
    atomicAdd(&cen_acc[k * Dd + t + 256], a1);
}

// ---- 3) finalize centroids: divide, bf16 copy, ||cen||_F^2 --------------
__global__ void k_cenfin(float* cen, const int* __restrict__ cnt,
                         ushort_t* cenb, float* scal) {
    int k = blockIdx.x, t = threadIdx.x;
    float c = (float)cnt[k];
    float inv = c > 0.f ? 1.0f / c : 0.f;
    float v0 = cen[k * Dd + t] * inv, v1 = cen[k * Dd + t + 256] * inv;
    cen[k * Dd + t] = v0;           cen[k * Dd + t + 256] = v1;
    cenb[k * Dd + t] = f2bf(v0);    cenb[k * Dd + t + 256] = f2bf(v1);
    float ss = v0 * v0 + v1 * v1;
    #pragma unroll
    for (int o = 32; o; o >>= 1) ss += __shfl_xor(ss, o);
    __shared__ float w[4];
    int lane = t & 63, wid = t >> 6;
    if (lane == 0) w[wid] = ss;
    __syncthreads();
    if (t == 0) atomicAdd(&scal[1], w[0] + w[1] + w[2] + w[3]);
}

// ---- 4) per-subject distances: block = (subject, quarter), cen in LDS ---
// Emits 2 atomics per block (4-way contention) instead of per-row atomics.
__global__ __launch_bounds__(256)
void k_dist(const float* __restrict__ X, const int* __restrict__ cnt,
            const int* __restrict__ mlist, const float* __restrict__ cen,
            float* sumsqrt, float* scal0part) {
    int k = blockIdx.x >> 2, q = blockIdx.x & 3;
    int t = threadIdx.x, wid = t >> 6, lane = t & 63;
    __shared__ __align__(16) float cl[Dd];
    *(float2*)(cl + t * 2) = *(const float2*)(cen + (size_t)k * Dd + t * 2);
    __syncthreads();
    int n = cnt[k]; if (n > MAXM) n = MAXM;
    int per = (n + 3) >> 2;
    int m0 = q * per, m1 = min(m0 + per, n);
    float acc_d = 0.f, acc_x2 = 0.f;
    for (int m = m0 + wid; m < m1; m += 4) {
        const float* row = cfrow(X, mlist[k * MAXM + m]);
        float d2 = 0.f, x2 = 0.f;
        #pragma unroll
        for (int j = 0; j < 2; ++j) {
            float4 x = *(const float4*)(row + lane * 8 + j * 4);
            float4 c = *(const float4*)(cl  + lane * 8 + j * 4);
            float e;
            e = x.x - c.x; d2 += e * e; x2 += x.x * x.x;
            e = x.y - c.y; d2 += e * e; x2 += x.y * x.y;
            e = x.z - c.z; d2 += e * e; x2 += x.z * x.z;
            e = x.w - c.w; d2 += e * e; x2 += x.w * x.w;
        }
        #pragma unroll
        for (int o = 32; o; o >>= 1) { d2 += __shfl_xor(d2, o); x2 += __shfl_xor(x2, o); }
        if (lane == 0) { acc_d += sqrtf(sqrtf(d2)); acc_x2 += x2; }  // sqrt(dist)=(d2)^(1/4)
    }
    __shared__ float wd[4], wx[4];
    if (lane == 0) { wd[wid] = acc_d; wx[wid] = acc_x2; }
    __syncthreads();
    if (t == 0) {
        atomicAdd(&sumsqrt[k],   wd[0] + wd[1] + wd[2] + wd[3]);
        atomicAdd(&scal0part[k], wx[0] + wx[1] + wx[2] + wx[3]);
    }
}

// ---- 5) density: stats -> sort -> quantile clip -> normalize -> colscale -
__global__ void k_density(const float* __restrict__ sumsqrt, const int* __restrict__ cnt,
                          const float* __restrict__ scal, const float* __restrict__ scal0part,
                          float* colscale) {
    __shared__ float sd[Kk];
    __shared__ float sb[Kk];
    int t = threadIdx.x;
    // fold per-subject ||x||^2 partials -> scal0
    sb[t] = scal0part[t];
    __syncthreads();
    for (int o = 128; o; o >>= 1) { if (t < o) sb[t] += sb[t + o]; __syncthreads(); }
    float scal0 = sb[0];
    __syncthreads();
    float c = (float)cnt[t];
    bool valid = c > 1.f;
    float draw = valid ? (sumsqrt[t] / c) / logf(c + 10.f) : -INFINITY;
    sb[t] = draw;
    __syncthreads();
    for (int o = 128; o; o >>= 1) { if (t < o) sb[t] = fmaxf(sb[t], sb[t + o]); __syncthreads(); }
    float dmax = sb[0];
    __syncthreads();
    float dens = valid ? draw : dmax;
    sd[t] = dens;
    __syncthreads();
    // bitonic sort ascending (256 values, 256 threads)
    for (int ksz = 2; ksz <= Kk; ksz <<= 1) {
        for (int j = ksz >> 1; j > 0; j >>= 1) {
            int ixj = t ^ j;
            if (ixj > t) {
                float a = sd[t], b = sd[ixj];
                bool up = ((t & ksz) == 0);
                if ((a > b) == up) { sd[t] = b; sd[ixj] = a; }
            }
            __syncthreads();
        }
    }
    float p1 = 0.1f * (Kk - 1); int i1 = (int)p1; float f1 = p1 - (float)i1;
    float p9 = 0.9f * (Kk - 1); int i9 = (int)p9; float f9 = p9 - (float)i9;
    float q10 = sd[i1] + f1 * (sd[i1 + 1] - sd[i1]);
    float q90 = sd[i9] + f9 * (sd[i9 + 1] - sd[i9]);
    float dcl = fminf(fmaxf(dens, q10), q90);
    __syncthreads();
    sb[t] = dcl;
    __syncthreads();
    for (int o = 128; o; o >>= 1) { if (t < o) sb[t] += sb[t + o]; __syncthreads(); }
    float mean = sb[0] / (float)Kk;
    float df = 0.1f * dcl / mean;
    colscale[t] = 1.0f / (sqrtf(scal0) * sqrtf(scal[1]) * df);
}

// ---- 6) fused bf16-MFMA GEMM (cf @ cen^T) + masked log-softmax loss -----
__global__ __launch_bounds__(512)
void k_loss(const float* __restrict__ X, const int* __restrict__ subject,
            const ushort_t* __restrict__ cenb, const float* __restrict__ colscale,
            float* loss_sum) {
    __shared__ __align__(16) ushort_t Alds[128 * 32];   // 8 KB
    __shared__ __align__(16) ushort_t Blds[256 * 32];   // 16 KB
    __shared__ float cs[256];
    __shared__ int sseg[128];
    __shared__ float blockloss;
    int t = threadIdx.x;
    int wid = t >> 6, lane = t & 63;
    int row0 = blockIdx.x * 128;
    if (t < 256) cs[t] = colscale[t];
    if (t < 128) { int gr = row0 + t; sseg[t] = subject[gr < Bn ? gr : gr - Bn]; }
    if (t == 0) blockloss = 0.f;

    f32x4 acc[16] = {};

    int ar = t >> 2, aq = t & 3;   // A staging: 4 threads/row, 8 floats each
    int bc = t >> 1, bh = t & 1;   // B staging: 2 threads/row, 16 bf16 each
    const float* asrc_base = cfrow(X, row0 + ar);

    for (int k0 = 0; k0 < Dd; k0 += 32) {
        __syncthreads();
        {   // stage A (fp32 -> bf16, XOR-swizzled 16B chunks)
            const float* src = asrc_base + k0 + aq * 8;
            float4 x0 = *(const float4*)src;
            float4 x1 = *(const float4*)(src + 4);
            us8 pk;
            pk[0] = f2bf(x0.x); pk[1] = f2bf(x0.y); pk[2] = f2bf(x0.z); pk[3] = f2bf(x0.w);
            pk[4] = f2bf(x1.x); pk[5] = f2bf(x1.y); pk[6] = f2bf(x1.z); pk[7] = f2bf(x1.w);
            int sw = aq ^ ((ar >> 1) & 3);
            *(us8*)(Alds + ar * 32 + sw * 8) = pk;
        }
        {   // stage B (cen bf16, XOR-swizzled)
            const ushort_t* src = cenb + bc * Dd + k0 + bh * 16;
            us8 b0 = *(const us8*)src;
            us8 b1 = *(const us8*)(src + 8);
            int r3 = (bc >> 1) & 3;
            *(us8*)(Blds + bc * 32 + ((2 * bh    ) ^ r3) * 8) = b0;
            *(us8*)(Blds + bc * 32 + ((2 * bh + 1) ^ r3) * 8) = b1;
        }
        __syncthreads();
        int q = lane >> 4;
        int rl = wid * 16 + (lane & 15);
        us8 araw = *(const us8*)(Alds + rl * 32 + (q ^ ((rl >> 1) & 3)) * 8);
        bf16x8 a = __builtin_bit_cast(bf16x8, araw);
        #pragma unroll
        for (int ct = 0; ct < 16; ++ct) {
            int cc = ct * 16 + (lane & 15);
            us8 braw = *(const us8*)(Blds + cc * 32 + (q ^ ((cc >> 1) & 3)) * 8);
            bf16x8 b = __builtin_bit_cast(bf16x8, braw);
            acc[ct] = __builtin_amdgcn_mfma_f32_16x16x32_bf16(a, b, acc[ct], 0, 0, 0);
        }
    }

    // epilogue: per-row masked lse + sum over 256 cols (16 lanes x 16 frags)
    int q = lane >> 4, cl = lane & 15;
    float lossw = 0.f;
    #pragma unroll
    for (int reg = 0; reg < 4; ++reg) {
        int rl = wid * 16 + q * 4 + reg;       // C layout: row=(lane>>4)*4+reg
        int s = sseg[rl];
        float mymax = -INFINITY;
        #pragma unroll
        for (int ct = 0; ct < 16; ++ct) {
            int c = ct * 16 + cl;
            float v = acc[ct][reg] * cs[c];
            if (c != s) mymax = fmaxf(mymax, v);
        }
        #pragma unroll
        for (int o = 1; o < 16; o <<= 1) mymax = fmaxf(mymax, __shfl_xor(mymax, o));
        float se = 0.f, sv = 0.f;
        #pragma unroll
        for (int ct = 0; ct < 16; ++ct) {
            int c = ct * 16 + cl;
            float v = acc[ct][reg] * cs[c];
            if (c != s) { se += __expf(v - mymax); sv += v; }
        }
        #pragma unroll
        for (int o = 1; o < 16; o <<= 1) { se += __shfl_xor(se, o); sv += __shfl_xor(sv, o); }
        if (cl == 0) lossw += (__logf(se) + mymax) - sv * (1.0f / (float)(Kk - 1));
    }
    if (cl == 0) atomicAdd(&blockloss, lossw);
    __syncthreads();
    if (t == 0) atomicAdd(loss_sum, blockloss);
}

// ---- 7) final scalar ------------------------------------------------------
__global__ void k_final(const float* __restrict__ loss_sum, float* out) {
    out[0] = loss_sum[0] / (float)TWOB;
}

extern "C" void kernel_launch(void* const* d_in, const int* in_sizes, int n_in,
                              void* d_out, int out_size, void* d_ws, size_t ws_size,
                              hipStream_t stream) {
    const float* X = (const float*)d_in[0];
    const int* subject = (const int*)d_in[1];
    float* out = (float*)d_out;
    float* ws = (float*)d_ws;

    float* cen       = ws;                                   // K*D fp32 (acc -> final)
    int*   cnt       = (int*)(ws + Kk * Dd);                 // K
    float* sumsqrt   = ws + Kk * Dd + Kk;                    // K
    float* scal0part = ws + Kk * Dd + 2 * Kk;                // K (per-subject ||x||^2 partials)
    float* scal      = ws + Kk * Dd + 3 * Kk;                // [1]=||cen||^2 [2]=loss
    float* colscale  = ws + Kk * Dd + 3 * Kk + 8;            // K
    ushort_t* cenb   = (ushort_t*)(ws + Kk * Dd + 4 * Kk + 8);             // K*D bf16
    int*   mlist     = (int*)(ws + Kk * Dd + 4 * Kk + 8 + (Kk * Dd) / 2);  // K*MAXM

    // zero all accumulators (cen_acc, cnt, sumsqrt, scal0part, scalars)
    hipMemsetAsync(ws, 0, (size_t)(Kk * Dd + 3 * Kk + 8) * sizeof(float), stream);

    k_count  <<<TWOB / 256, 256, 0, stream>>>(subject, cnt, mlist);
    k_cent   <<<dim3(MC, Kk), 256, 0, stream>>>(X, cnt, mlist, cen);
    k_cenfin <<<Kk, 256, 0, stream>>>(cen, cnt, cenb, scal);
    k_dist   <<<Kk * 4, 256, 0, stream>>>(X, cnt, mlist, cen, sumsqrt, scal0part);
    k_density<<<1, 256, 0, stream>>>(sumsqrt, cnt, scal, scal0part, colscale);
    k_loss   <<<TWOB / 128, 512, 0, stream>>>(X, subject, cenb, colscale, &scal[2]);
    k_final  <<<1, 1, 0, stream>>>(&scal[2], out);
}